// Round 6
// baseline (511.353 us; speedup 1.0000x reference)
//
#include <hip/hip_runtime.h>
#include <hip/hip_bf16.h>

#define DEVI __device__ __forceinline__

typedef __bf16 bf16x8 __attribute__((ext_vector_type(8)));
typedef float f32x4 __attribute__((ext_vector_type(4)));
typedef unsigned short u16x4 __attribute__((ext_vector_type(4)));
typedef unsigned int u32x2 __attribute__((ext_vector_type(2)));
typedef int i32x4 __attribute__((ext_vector_type(4)));

constexpr int Nn = 2, Ss = 2048, Ee = 1024, Hh = 16;
constexpr int Ms = Nn * Ss;                       // 4096 rows
constexpr float SCALE = 0.022097086912079608f;    // 1/sqrt(2048) -- key-length scaling!

// workspace layout (bf16 elements)
constexpr size_t SZ_X   = (size_t)Ms * Ee;        // 4,194,304
constexpr size_t OFF_QB = 0;                      // Q projected [Ms][Ee]
constexpr size_t OFF_KB = SZ_X;                   // K projected [Ms][Ee]
constexpr size_t OFF_VB = 2 * SZ_X;               // V projected TRANSPOSED [Ee][Ms]
constexpr size_t OFF_XQ = 3 * SZ_X;               // bf16 inputs (3)
constexpr size_t OFF_W  = 6 * SZ_X;               // 4 weights, each Ee*Ee
constexpr size_t OFF_ATTN = OFF_XQ;               // attention out aliases XQ (dead by then)

DEVI unsigned short f2bf(float f) {               // RNE f32->bf16 (no NaN in this data)
  unsigned int u = __builtin_bit_cast(unsigned int, f);
  u += 0x7fffu + ((u >> 16) & 1u);
  return (unsigned short)(u >> 16);
}

DEVI void async16(const void* g, void* l) {
  __builtin_amdgcn_global_load_lds(
      (const __attribute__((address_space(1))) void*)g,
      (__attribute__((address_space(3))) void*)l, 16, 0, 0);
}

DEVI f32x4 mfma_bf16(bf16x8 a, bf16x8 b, f32x4 c) {
  return __builtin_amdgcn_mfma_f32_16x16x32_bf16(a, b, c, 0, 0, 0);
}

// ---------------- fp32 -> bf16 convert, z-batched over up to 4 sources -------------
__global__ __launch_bounds__(256) void cvt_batch(
    const float* __restrict__ s0, const float* __restrict__ s1,
    const float* __restrict__ s2, const float* __restrict__ s3,
    unsigned short* __restrict__ dbase, size_t dstride, int n4)
{
  const float* s = (blockIdx.z == 0) ? s0 : (blockIdx.z == 1) ? s1
                 : (blockIdx.z == 2) ? s2 : s3;
  unsigned short* d = dbase + (size_t)blockIdx.z * dstride;
  const int i = blockIdx.x * 256 + threadIdx.x;
  if (i >= n4) return;
  const float4 v = reinterpret_cast<const float4*>(s)[i];
  u16x4 o = { f2bf(v.x), f2bf(v.y), f2bf(v.z), f2bf(v.w) };
  reinterpret_cast<u16x4*>(d)[i] = o;
}

// ---------------- 128x128 bf16 GEMM, C = A @ B^T  (A:[M,K=1024], B:[N,K=1024]) -----
template <bool WRITE_F32>
__global__ __launch_bounds__(256) void gemm_bt(
    const unsigned short* __restrict__ Abase,
    const unsigned short* __restrict__ Bbase,
    unsigned short* __restrict__ Cbase,
    float* __restrict__ Cf,
    const float* __restrict__ bias,
    size_t strideA, size_t strideB, size_t strideC, int ldC)
{
  constexpr int K = 1024;
  __shared__ unsigned short As[128 * 32];
  __shared__ unsigned short Bs[128 * 32];

  const int z = blockIdx.z;
  const unsigned short* A = Abase + (size_t)z * strideA;
  const unsigned short* B = Bbase + (size_t)z * strideB;

  const int tid = threadIdx.x;
  const int lane = tid & 63, w = tid >> 6;
  const int lr = lane & 15, lg = lane >> 4;
  const int m0 = blockIdx.y * 128, n0 = blockIdx.x * 128;
  const int wr = (w >> 1) * 64, wc = (w & 1) * 64;

  const f32x4 zero = {0.f, 0.f, 0.f, 0.f};
  f32x4 acc[4][4];
  for (int a = 0; a < 4; ++a)
    for (int b = 0; b < 4; ++b) acc[a][b] = zero;

  for (int k0 = 0; k0 < K; k0 += 32) {
#pragma unroll
    for (int ii = 0; ii < 2; ++ii) {
      const int i = 2 * w + ii;
      const int boff = i * 1024 + lane * 16;
      const int row = boff >> 6;
      const int colb = boff & 63;
      const char* ga = (const char*)A + ((size_t)(m0 + row) * K + k0) * 2 + colb;
      const char* gb = (const char*)B + ((size_t)(n0 + row) * K + k0) * 2 + colb;
      async16(ga, (char*)As + i * 1024);
      async16(gb, (char*)Bs + i * 1024);
    }
    __syncthreads();

    bf16x8 aF[4], bF[4];
#pragma unroll
    for (int rb = 0; rb < 4; ++rb)
      aF[rb] = *(const bf16x8*)(As + (wr + rb * 16 + lr) * 32 + lg * 8);
#pragma unroll
    for (int cb = 0; cb < 4; ++cb)
      bF[cb] = *(const bf16x8*)(Bs + (wc + cb * 16 + lr) * 32 + lg * 8);
#pragma unroll
    for (int rb = 0; rb < 4; ++rb)
#pragma unroll
      for (int cb = 0; cb < 4; ++cb)
        acc[rb][cb] = mfma_bf16(aF[rb], bF[cb], acc[rb][cb]);
    __syncthreads();
  }

#pragma unroll
  for (int rb = 0; rb < 4; ++rb) {
#pragma unroll
    for (int cb = 0; cb < 4; ++cb) {
#pragma unroll
      for (int j = 0; j < 4; ++j) {
        const int row = m0 + wr + rb * 16 + lg * 4 + j;
        const int col = n0 + wc + cb * 16 + lr;
        const float v = acc[rb][cb][j];
        if constexpr (WRITE_F32) {
          Cf[(size_t)row * ldC + col] = v + bias[col];
        } else {
          unsigned short* C = Cbase + (size_t)z * strideC;
          C[(size_t)row * ldC + col] = f2bf(v);
        }
      }
    }
  }
}

// ---------------- fused masked attention, S^T orientation --------------------------
// mfma(K,Q) -> lane holds S[k = cb*16+lg*4+j][q = qb*16+lr]: k-in-regs, q-in-lanes.
//  * mask: 8 coalesced dwordx4 loads/lane/tile (16 consecutive ints per 4-lane group)
//  * P staging: 8 ds_write_b64 (paired bf16 pack) + 4 ds_read_b128, stride 144 B
//  * K/V: global_load_lds staging, pre-swizzled source, double-buffered, raw barrier
// MEASUREMENT ROUND: grid = 3*512. rep = blockIdx>>9. rep0 writes real output;
// reps 1,2 read disjoint mask slices and sink results via asm keep-alive (no DCE,
// no stores) -> attention dispatch ~3x -> surfaces in rocprof top-5 with counters.
__global__ __launch_bounds__(256) void attn_kernel(
    const unsigned short* __restrict__ Qb,
    const unsigned short* __restrict__ Kb,     // [Ms][Ee]
    const unsigned short* __restrict__ Vtb,    // [Ee][Ms]  (pre-transposed)
    const int* __restrict__ mask,
    unsigned short* __restrict__ Ob)
{
  __shared__ unsigned short Kl0[64 * 64], Kl1[64 * 64];
  __shared__ unsigned short Vl0[64 * 64], Vl1[64 * 64];
  __shared__ unsigned short Pw[4 * 32 * 72];   // per-wave P [32 q][72 bf16], 144 B rows

  const int tid = threadIdx.x;
  const int lane = tid & 63, w = tid >> 6;
  const int lr = lane & 15, lg = lane >> 4;

  const int lid = blockIdx.x;
  const int rep = lid >> 9;                      // 0 real, 1/2 measurement replicas
  const int l9 = lid & 511;
  const int xcd = l9 & 7, slot = l9 >> 3;
  const int g = xcd + 8 * (slot >> 4);           // nh group 0..31
  const int n = g >> 4, h = g & 15;
  const int q0 = (slot & 15) * 128;

  // Q fragments: wave w owns q rows [q0+32w, q0+32w+32)
  bf16x8 aQ[2][2];
#pragma unroll
  for (int qb = 0; qb < 2; ++qb) {
    const unsigned short* qp =
        Qb + ((size_t)(n * Ss + q0 + w * 32 + qb * 16 + lr)) * Ee + h * 64 + lg * 8;
    aQ[qb][0] = *(const bf16x8*)(qp);
    aQ[qb][1] = *(const bf16x8*)(qp + 32);
  }

  // staging geometry (16B chunk sig of the 8KB [64][64] tile, source pre-swizzled)
  const int sig0 = (w * 2) * 64 + lane;
  const int row0 = sig0 >> 3;
  const int c0 = (sig0 & 7) ^ (row0 & 7);
  const int row1 = row0 + 8;
  const int c1 = (sig0 & 7) ^ (row1 & 7);
  const int ldsb0 = (w * 2 + 0) * 1024;
  const int ldsb1 = (w * 2 + 1) * 1024;

  const unsigned short* kp0 = Kb + ((size_t)(n * Ss + row0) * Ee + h * 64 + c0 * 8);
  const unsigned short* kp1 = Kb + ((size_t)(n * Ss + row1) * Ee + h * 64 + c1 * 8);
  const unsigned short* vp0 = Vtb + ((size_t)(h * 64 + row0) * Ms + n * Ss + c0 * 8);
  const unsigned short* vp1 = Vtb + ((size_t)(h * 64 + row1) * Ms + n * Ss + c1 * 8);

  // mask slice: rep 0 = real (n,h); reps read disjoint slices (same volume)
  const int nm = (n + rep) & 1;
  const int hm = (h + rep * 5) & 15;
  const int* m0p = mask + ((size_t)(nm * Hh + hm) * Ss + (q0 + w * 32 + lr)) * Ss
                        + lg * 4;
  const int* m1p = m0p + (size_t)16 * Ss;

  const f32x4 zero = {0.f, 0.f, 0.f, 0.f};
  f32x4 oacc[2][4];
#pragma unroll
  for (int qb = 0; qb < 2; ++qb)
#pragma unroll
    for (int db = 0; db < 4; ++db) oacc[qb][db] = zero;
  float rs[2] = {0.f, 0.f};

  char* const PwW = (char*)Pw + w * (32 * 144);  // wave-private P slice

  // ---- prologue: stage tile 0, mask tile 0 into regs ----
  async16(kp0, (char*)Kl0 + ldsb0);
  async16(kp1, (char*)Kl0 + ldsb1);
  async16(vp0, (char*)Vl0 + ldsb0);
  async16(vp1, (char*)Vl0 + ldsb1);
  kp0 += (size_t)64 * Ee; kp1 += (size_t)64 * Ee; vp0 += 64; vp1 += 64;

  i32x4 mq[2][4];
#pragma unroll
  for (int cb = 0; cb < 4; ++cb) {
    mq[0][cb] = __builtin_nontemporal_load((const i32x4*)(m0p + cb * 16));
    mq[1][cb] = __builtin_nontemporal_load((const i32x4*)(m1p + cb * 16));
  }

  int cur = 0;
  for (int kt = 0; kt < Ss / 64; ++kt) {
    // everything issued last iteration (stage(kt), mask(kt)) has landed; sync
    asm volatile("s_waitcnt vmcnt(0)" ::: "memory");
    __builtin_amdgcn_s_barrier();

    const unsigned short* Kc = cur ? Kl1 : Kl0;
    const unsigned short* Vc = cur ? Vl1 : Vl0;
    unsigned short* Kn = cur ? Kl0 : Kl1;
    unsigned short* Vn = cur ? Vl0 : Vl1;

    // compress mask(kt): bit (qb*16 + cb*4 + j)
    unsigned mbits = 0;
#pragma unroll
    for (int qb = 0; qb < 2; ++qb)
#pragma unroll
      for (int cb = 0; cb < 4; ++cb)
#pragma unroll
        for (int j = 0; j < 4; ++j)
          mbits |= (mq[qb][cb][j] != 0 ? 1u : 0u) << (qb * 16 + cb * 4 + j);

    if (kt + 1 < Ss / 64) {
      async16(kp0, (char*)Kn + ldsb0);
      async16(kp1, (char*)Kn + ldsb1);
      async16(vp0, (char*)Vn + ldsb0);
      async16(vp1, (char*)Vn + ldsb1);
      kp0 += (size_t)64 * Ee; kp1 += (size_t)64 * Ee; vp0 += 64; vp1 += 64;
      const int ko = (kt + 1) * 64;
#pragma unroll
      for (int cb = 0; cb < 4; ++cb) {
        mq[0][cb] = __builtin_nontemporal_load((const i32x4*)(m0p + ko + cb * 16));
        mq[1][cb] = __builtin_nontemporal_load((const i32x4*)(m1p + ko + cb * 16));
      }
    }

    // S^T = K Q^T per 16-k block; softmax + paired P pack + ds_write_b64
#pragma unroll
    for (int cb = 0; cb < 4; ++cb) {
      const int row = cb * 16 + lr;
      const bf16x8 kF0 = *(const bf16x8*)((const char*)Kc + row * 128 +
                                          ((lg ^ (row & 7)) * 16));
      const bf16x8 kF1 = *(const bf16x8*)((const char*)Kc + row * 128 +
                                          (((4 + lg) ^ (row & 7)) * 16));
#pragma unroll
      for (int qb = 0; qb < 2; ++qb) {
        f32x4 a = mfma_bf16(kF0, aQ[qb][0], zero);
        a = mfma_bf16(kF1, aQ[qb][1], a);
        float p[4];
#pragma unroll
        for (int j = 0; j < 4; ++j) {
          const unsigned bit = (mbits >> (qb * 16 + cb * 4 + j)) & 1u;
          p[j] = bit ? __expf(a[j] * SCALE) : 0.f;
        }
        rs[qb] += (p[0] + p[1]) + (p[2] + p[3]);
        u32x2 pd;
        pd[0] = (unsigned)f2bf(p[0]) | ((unsigned)f2bf(p[1]) << 16);
        pd[1] = (unsigned)f2bf(p[2]) | ((unsigned)f2bf(p[3]) << 16);
        *(u32x2*)(PwW + (qb * 16 + lr) * 144 + cb * 32 + lg * 8) = pd;
      }
    }

    // O += P V : aP from wave-private Pw (RAW ordered via lgkmcnt)
    bf16x8 aP[2][2];
#pragma unroll
    for (int qb = 0; qb < 2; ++qb)
#pragma unroll
      for (int kc = 0; kc < 2; ++kc)
        aP[qb][kc] = *(const bf16x8*)(PwW + (qb * 16 + lr) * 144 + kc * 64 + lg * 16);
#pragma unroll
    for (int db = 0; db < 4; ++db) {
      const int row = db * 16 + lr;
#pragma unroll
      for (int kc = 0; kc < 2; ++kc) {
        const bf16x8 bV = *(const bf16x8*)((const char*)Vc + row * 128 +
                                           (((kc * 4 + lg) ^ (row & 7)) * 16));
#pragma unroll
        for (int qb = 0; qb < 2; ++qb)
          oacc[qb][db] = mfma_bf16(aP[qb][kc], bV, oacc[qb][db]);
      }
    }

    cur ^= 1;
  }

  if (rep) {  // measurement replicas: keep all work live, store nothing
    float chk = rs[0] + rs[1];
#pragma unroll
    for (int qb = 0; qb < 2; ++qb)
#pragma unroll
      for (int db = 0; db < 4; ++db)
#pragma unroll
        for (int j = 0; j < 4; ++j) chk += oacc[qb][db][j];
    asm volatile("" :: "v"(chk));
    return;
  }

  // rowsum: reduce across the 4 lg groups (q = qb*16+lr), then fetch per-output-q
  float inv[2][4];
#pragma unroll
  for (int qb = 0; qb < 2; ++qb) {
    float r = rs[qb];
    r += __shfl_xor(r, 16, 64);
    r += __shfl_xor(r, 32, 64);
#pragma unroll
    for (int j = 0; j < 4; ++j)
      inv[qb][j] = 1.0f / __shfl(r, lg * 4 + j, 64);
  }
#pragma unroll
  for (int qb = 0; qb < 2; ++qb)
#pragma unroll
    for (int db = 0; db < 4; ++db)
#pragma unroll
      for (int j = 0; j < 4; ++j) {
        const int qr = q0 + w * 32 + qb * 16 + lg * 4 + j;
        Ob[((size_t)(n * Ss + qr)) * Ee + h * 64 + db * 16 + lr] =
            f2bf(oacc[qb][db][j] * inv[qb][j]);
      }
}

// -----------------------------------------------------------------------------------
extern "C" void kernel_launch(void* const* d_in, const int* in_sizes, int n_in,
                              void* d_out, int out_size, void* d_ws, size_t ws_size,
                              hipStream_t stream) {
  const float* qin = (const float*)d_in[0];
  const float* kin = (const float*)d_in[1];
  const float* vin = (const float*)d_in[2];
  const int*   msk = (const int*)d_in[3];
  const float* Wq  = (const float*)d_in[4];
  const float* Wk  = (const float*)d_in[5];
  const float* Wv  = (const float*)d_in[6];
  const float* Wo  = (const float*)d_in[7];
  const float* bo  = (const float*)d_in[8];
  unsigned short* ws = (unsigned short*)d_ws;
  const size_t EE = (size_t)Ee * Ee;

  // 1) convert inputs + weights to bf16
  cvt_batch<<<dim3((unsigned)(SZ_X / 4 / 256), 1, 3), 256, 0, stream>>>(
      qin, kin, vin, nullptr, ws + OFF_XQ, SZ_X, (int)(SZ_X / 4));
  cvt_batch<<<dim3((unsigned)(EE / 4 / 256), 1, 4), 256, 0, stream>>>(
      Wq, Wk, Wv, Wo, ws + OFF_W, EE, (int)(EE / 4));

  // 2a) Q/K projections (z-batched):  C[m][e] = X @ W^T
  gemm_bt<false><<<dim3(8, 32, 2), 256, 0, stream>>>(
      ws + OFF_XQ, ws + OFF_W, ws + OFF_QB, nullptr, nullptr,
      SZ_X, EE, SZ_X, Ee);

  // 2b) V projection, TRANSPOSED output:  Vt[e][m] = Wv @ Xv^T
  gemm_bt<false><<<dim3(32, 8, 1), 256, 0, stream>>>(
      ws + OFF_W + 2 * EE, ws + OFF_XQ + 2 * SZ_X, ws + OFF_VB, nullptr, nullptr,
      0, 0, 0, Ms);

  // 3) masked attention — MEASUREMENT: 3x replicated (rep0 real, reps sink)
  attn_kernel<<<dim3(1536), 256, 0, stream>>>(
      ws + OFF_QB, ws + OFF_KB, ws + OFF_VB, msk, ws + OFF_ATTN);

  // 4) output projection + bias -> fp32 d_out
  gemm_bt<true><<<dim3(8, 32, 1), 256, 0, stream>>>(
      ws + OFF_ATTN, ws + OFF_W + 3 * EE, nullptr,
      (float*)d_out, bo, 0, 0, 0, Ee);
}

// Round 7
// 247.192 us; speedup vs baseline: 2.0686x; 2.0686x over previous
//
#include <hip/hip_runtime.h>
#include <hip/hip_bf16.h>

#define DEVI __device__ __forceinline__

typedef __bf16 bf16x8 __attribute__((ext_vector_type(8)));
typedef float f32x4 __attribute__((ext_vector_type(4)));
typedef unsigned short u16x4 __attribute__((ext_vector_type(4)));
typedef unsigned int u32x2 __attribute__((ext_vector_type(2)));
typedef int i32x4 __attribute__((ext_vector_type(4)));

constexpr int Nn = 2, Ss = 2048, Ee = 1024, Hh = 16;
constexpr int Ms = Nn * Ss;                       // 4096 rows
constexpr float SCALE = 0.022097086912079608f;    // 1/sqrt(2048) -- key-length scaling!

// workspace layout (bf16 elements)
constexpr size_t SZ_X   = (size_t)Ms * Ee;        // 4,194,304
constexpr size_t OFF_QB = 0;                      // Q projected [Ms][Ee]
constexpr size_t OFF_KB = SZ_X;                   // K projected [Ms][Ee]
constexpr size_t OFF_VB = 2 * SZ_X;               // V projected TRANSPOSED [Ee][Ms]
constexpr size_t OFF_XQ = 3 * SZ_X;               // bf16 inputs (3)
constexpr size_t OFF_W  = 6 * SZ_X;               // 4 weights, each Ee*Ee
constexpr size_t OFF_ATTN = OFF_XQ;               // attention out aliases XQ (dead by then)

DEVI unsigned short f2bf(float f) {               // RNE f32->bf16 (no NaN in this data)
  unsigned int u = __builtin_bit_cast(unsigned int, f);
  u += 0x7fffu + ((u >> 16) & 1u);
  return (unsigned short)(u >> 16);
}

DEVI void async16(const void* g, void* l) {
  __builtin_amdgcn_global_load_lds(
      (const __attribute__((address_space(1))) void*)g,
      (__attribute__((address_space(3))) void*)l, 16, 0, 0);
}

DEVI f32x4 mfma_bf16(bf16x8 a, bf16x8 b, f32x4 c) {
  return __builtin_amdgcn_mfma_f32_16x16x32_bf16(a, b, c, 0, 0, 0);
}

DEVI unsigned cvt_pk_bf16(float lo, float hi) {   // v_cvt_pk_bf16_f32: [hi|lo]
  unsigned r;
  asm("v_cvt_pk_bf16_f32 %0, %1, %2" : "=v"(r) : "v"(lo), "v"(hi));
  return r;
}

// ---------------- fp32 -> bf16 convert, z-batched over up to 4 sources -------------
__global__ __launch_bounds__(256) void cvt_batch(
    const float* __restrict__ s0, const float* __restrict__ s1,
    const float* __restrict__ s2, const float* __restrict__ s3,
    unsigned short* __restrict__ dbase, size_t dstride, int n4)
{
  const float* s = (blockIdx.z == 0) ? s0 : (blockIdx.z == 1) ? s1
                 : (blockIdx.z == 2) ? s2 : s3;
  unsigned short* d = dbase + (size_t)blockIdx.z * dstride;
  const int i = blockIdx.x * 256 + threadIdx.x;
  if (i >= n4) return;
  const float4 v = reinterpret_cast<const float4*>(s)[i];
  u16x4 o = { f2bf(v.x), f2bf(v.y), f2bf(v.z), f2bf(v.w) };
  reinterpret_cast<u16x4*>(d)[i] = o;
}

// ---------------- 128x128 bf16 GEMM, C = A @ B^T  (A:[M,K=1024], B:[N,K=1024]) -----
template <bool WRITE_F32>
__global__ __launch_bounds__(256) void gemm_bt(
    const unsigned short* __restrict__ Abase,
    const unsigned short* __restrict__ Bbase,
    unsigned short* __restrict__ Cbase,
    float* __restrict__ Cf,
    const float* __restrict__ bias,
    size_t strideA, size_t strideB, size_t strideC, int ldC)
{
  constexpr int K = 1024;
  __shared__ unsigned short As[128 * 32];
  __shared__ unsigned short Bs[128 * 32];

  const int z = blockIdx.z;
  const unsigned short* A = Abase + (size_t)z * strideA;
  const unsigned short* B = Bbase + (size_t)z * strideB;

  const int tid = threadIdx.x;
  const int lane = tid & 63, w = tid >> 6;
  const int lr = lane & 15, lg = lane >> 4;
  const int m0 = blockIdx.y * 128, n0 = blockIdx.x * 128;
  const int wr = (w >> 1) * 64, wc = (w & 1) * 64;

  const f32x4 zero = {0.f, 0.f, 0.f, 0.f};
  f32x4 acc[4][4];
  for (int a = 0; a < 4; ++a)
    for (int b = 0; b < 4; ++b) acc[a][b] = zero;

  for (int k0 = 0; k0 < K; k0 += 32) {
#pragma unroll
    for (int ii = 0; ii < 2; ++ii) {
      const int i = 2 * w + ii;
      const int boff = i * 1024 + lane * 16;
      const int row = boff >> 6;
      const int colb = boff & 63;
      const char* ga = (const char*)A + ((size_t)(m0 + row) * K + k0) * 2 + colb;
      const char* gb = (const char*)B + ((size_t)(n0 + row) * K + k0) * 2 + colb;
      async16(ga, (char*)As + i * 1024);
      async16(gb, (char*)Bs + i * 1024);
    }
    __syncthreads();

    bf16x8 aF[4], bF[4];
#pragma unroll
    for (int rb = 0; rb < 4; ++rb)
      aF[rb] = *(const bf16x8*)(As + (wr + rb * 16 + lr) * 32 + lg * 8);
#pragma unroll
    for (int cb = 0; cb < 4; ++cb)
      bF[cb] = *(const bf16x8*)(Bs + (wc + cb * 16 + lr) * 32 + lg * 8);
#pragma unroll
    for (int rb = 0; rb < 4; ++rb)
#pragma unroll
      for (int cb = 0; cb < 4; ++cb)
        acc[rb][cb] = mfma_bf16(aF[rb], bF[cb], acc[rb][cb]);
    __syncthreads();
  }

#pragma unroll
  for (int rb = 0; rb < 4; ++rb) {
#pragma unroll
    for (int cb = 0; cb < 4; ++cb) {
#pragma unroll
      for (int j = 0; j < 4; ++j) {
        const int row = m0 + wr + rb * 16 + lg * 4 + j;
        const int col = n0 + wc + cb * 16 + lr;
        const float v = acc[rb][cb][j];
        if constexpr (WRITE_F32) {
          Cf[(size_t)row * ldC + col] = v + bias[col];
        } else {
          unsigned short* C = Cbase + (size_t)z * strideC;
          C[(size_t)row * ldC + col] = f2bf(v);
        }
      }
    }
  }
}

// ---------------- fused masked attention, S^T orientation, VALU-lean ---------------
// mfma(K,Q): lane holds S[k][q]. Manual 2x unroll of the k-tile loop ping-pongs
// LDS buffers AND mask register sets at compile time (no cur-selects, no copies).
// All swizzled DS offsets precomputed per-thread. P-pack via v_cvt_pk_bf16_f32.
// Mask gating selects directly on prefetched registers (v_cmp+cndmask, 2 ops/elem).
__global__ __launch_bounds__(256) void attn_kernel(
    const unsigned short* __restrict__ Qb,
    const unsigned short* __restrict__ Kb,     // [Ms][Ee]
    const unsigned short* __restrict__ Vtb,    // [Ee][Ms]  (pre-transposed)
    const int* __restrict__ mask,
    unsigned short* __restrict__ Ob)
{
  __shared__ unsigned short Kl0[64 * 64], Kl1[64 * 64];
  __shared__ unsigned short Vl0[64 * 64], Vl1[64 * 64];
  __shared__ unsigned short Pw[4 * 32 * 72];   // per-wave P [32 q][144 B rows]

  const int tid = threadIdx.x;
  const int lane = tid & 63, w = tid >> 6;
  const int lr = lane & 15, lg = lane >> 4;

  // XCD-locality decode
  const int lid = blockIdx.x;
  const int xcd = lid & 7, slot = lid >> 3;
  const int g = xcd + 8 * (slot >> 4);           // nh group 0..31
  const int n = g >> 4, h = g & 15;
  const int q0 = (slot & 15) * 128;

  // Q fragments: wave w owns q rows [q0+32w, q0+32w+32)
  bf16x8 aQ[2][2];
#pragma unroll
  for (int qb = 0; qb < 2; ++qb) {
    const unsigned short* qp =
        Qb + ((size_t)(n * Ss + q0 + w * 32 + qb * 16 + lr)) * Ee + h * 64 + lg * 8;
    aQ[qb][0] = *(const bf16x8*)(qp);
    aQ[qb][1] = *(const bf16x8*)(qp + 32);
  }

  // staging geometry (16B chunk sig of the 8KB [64][64] tile, source pre-swizzled)
  const int sig0 = (w * 2) * 64 + lane;
  const int row0 = sig0 >> 3;
  const int c0 = (sig0 & 7) ^ (row0 & 7);
  const int row1 = row0 + 8;
  const int c1 = (sig0 & 7) ^ (row1 & 7);
  const int ldsb0 = (w * 2 + 0) * 1024;
  const int ldsb1 = (w * 2 + 1) * 1024;

  const unsigned short* kp0 = Kb + ((size_t)(n * Ss + row0) * Ee + h * 64 + c0 * 8);
  const unsigned short* kp1 = Kb + ((size_t)(n * Ss + row1) * Ee + h * 64 + c1 * 8);
  const unsigned short* vp0 = Vtb + ((size_t)(h * 64 + row0) * Ms + n * Ss + c0 * 8);
  const unsigned short* vp1 = Vtb + ((size_t)(h * 64 + row1) * Ms + n * Ss + c1 * 8);

  const int* m0p = mask + ((size_t)(n * Hh + h) * Ss + (q0 + w * 32 + lr)) * Ss
                        + lg * 4;
  const int* m1p = m0p + (size_t)16 * Ss;

  // precomputed swizzled DS byte offsets (per-thread constants)
  int koff[4][2];                                // K/V frag reads (same formula)
#pragma unroll
  for (int cb = 0; cb < 4; ++cb) {
    const int row = cb * 16 + lr;
    koff[cb][0] = row * 128 + ((lg ^ (row & 7)) * 16);
    koff[cb][1] = row * 128 + (((4 + lg) ^ (row & 7)) * 16);
  }
  char* const PwW = (char*)Pw + w * (32 * 144);
  int pwo[2], pro[2];                            // P write / read bases per qb
#pragma unroll
  for (int qb = 0; qb < 2; ++qb) {
    pwo[qb] = (qb * 16 + lr) * 144 + lg * 8;
    pro[qb] = (qb * 16 + lr) * 144 + lg * 16;
  }

  const f32x4 zero = {0.f, 0.f, 0.f, 0.f};
  f32x4 oacc[2][4];
#pragma unroll
  for (int qb = 0; qb < 2; ++qb)
#pragma unroll
    for (int db = 0; db < 4; ++db) oacc[qb][db] = zero;
  float rs[2] = {0.f, 0.f};

  // ---- prologue: stage tile 0 into buf0, mask tile 0 into set A ----
  async16(kp0, (char*)Kl0 + ldsb0);
  async16(kp1, (char*)Kl0 + ldsb1);
  async16(vp0, (char*)Vl0 + ldsb0);
  async16(vp1, (char*)Vl0 + ldsb1);
  kp0 += (size_t)64 * Ee; kp1 += (size_t)64 * Ee; vp0 += 64; vp1 += 64;

  i32x4 mqA[2][4], mqB[2][4];
#pragma unroll
  for (int cb = 0; cb < 4; ++cb) {
    mqA[0][cb] = __builtin_nontemporal_load((const i32x4*)(m0p + cb * 16));
    mqA[1][cb] = __builtin_nontemporal_load((const i32x4*)(m1p + cb * 16));
  }

  auto tile = [&](const unsigned short* KC, const unsigned short* VC,
                  unsigned short* KN, unsigned short* VN,
                  i32x4 (&MQC)[2][4], i32x4 (&MQN)[2][4], bool pf) {
    // everything issued last body (stage, mask) has landed; sync
    asm volatile("s_waitcnt vmcnt(0)" ::: "memory");
    __builtin_amdgcn_s_barrier();

    if (pf) {
      async16(kp0, (char*)KN + ldsb0);
      async16(kp1, (char*)KN + ldsb1);
      async16(vp0, (char*)VN + ldsb0);
      async16(vp1, (char*)VN + ldsb1);
      kp0 += (size_t)64 * Ee; kp1 += (size_t)64 * Ee; vp0 += 64; vp1 += 64;
#pragma unroll
      for (int cb = 0; cb < 4; ++cb) {
        MQN[0][cb] = __builtin_nontemporal_load((const i32x4*)(m0p + 64 + cb * 16));
        MQN[1][cb] = __builtin_nontemporal_load((const i32x4*)(m1p + 64 + cb * 16));
      }
    }
    m0p += 64; m1p += 64;

    // S^T = K Q^T per 16-k block; gated exp; cvt_pk pack; ds_write_b64
#pragma unroll
    for (int cb = 0; cb < 4; ++cb) {
      const bf16x8 kF0 = *(const bf16x8*)((const char*)KC + koff[cb][0]);
      const bf16x8 kF1 = *(const bf16x8*)((const char*)KC + koff[cb][1]);
#pragma unroll
      for (int qb = 0; qb < 2; ++qb) {
        f32x4 a = mfma_bf16(kF0, aQ[qb][0], zero);
        a = mfma_bf16(kF1, aQ[qb][1], a);
        float p[4];
#pragma unroll
        for (int j = 0; j < 4; ++j)
          p[j] = MQC[qb][cb][j] ? __expf(a[j] * SCALE) : 0.f;
        rs[qb] += (p[0] + p[1]) + (p[2] + p[3]);
        u32x2 pd = { cvt_pk_bf16(p[0], p[1]), cvt_pk_bf16(p[2], p[3]) };
        *(u32x2*)(PwW + pwo[qb] + cb * 32) = pd;
      }
    }

    // O += P V  (Pw rows wave-private; compiler orders the LDS RAW via lgkmcnt)
    bf16x8 aP[2][2];
#pragma unroll
    for (int qb = 0; qb < 2; ++qb) {
      aP[qb][0] = *(const bf16x8*)(PwW + pro[qb]);
      aP[qb][1] = *(const bf16x8*)(PwW + pro[qb] + 64);
    }
#pragma unroll
    for (int db = 0; db < 4; ++db) {
#pragma unroll
      for (int kc = 0; kc < 2; ++kc) {
        const bf16x8 bV = *(const bf16x8*)((const char*)VC + koff[db][kc]);
#pragma unroll
        for (int qb = 0; qb < 2; ++qb)
          oacc[qb][db] = mfma_bf16(aP[qb][kc], bV, oacc[qb][db]);
      }
    }
  };

  for (int kt2 = 0; kt2 < 16; ++kt2) {
    tile(Kl0, Vl0, Kl1, Vl1, mqA, mqB, true);
    tile(Kl1, Vl1, Kl0, Vl0, mqB, mqA, kt2 != 15);
  }

  // rowsum: reduce across the 4 lg groups (q = qb*16+lr), then fetch per-output-q
  float inv[2][4];
#pragma unroll
  for (int qb = 0; qb < 2; ++qb) {
    float r = rs[qb];
    r += __shfl_xor(r, 16, 64);
    r += __shfl_xor(r, 32, 64);
#pragma unroll
    for (int j = 0; j < 4; ++j)
      inv[qb][j] = 1.0f / __shfl(r, lg * 4 + j, 64);
  }
#pragma unroll
  for (int qb = 0; qb < 2; ++qb)
#pragma unroll
    for (int db = 0; db < 4; ++db)
#pragma unroll
      for (int j = 0; j < 4; ++j) {
        const int qr = q0 + w * 32 + qb * 16 + lg * 4 + j;
        Ob[((size_t)(n * Ss + qr)) * Ee + h * 64 + db * 16 + lr] =
            f2bf(oacc[qb][db][j] * inv[qb][j]);
      }
}

// -----------------------------------------------------------------------------------
extern "C" void kernel_launch(void* const* d_in, const int* in_sizes, int n_in,
                              void* d_out, int out_size, void* d_ws, size_t ws_size,
                              hipStream_t stream) {
  const float* qin = (const float*)d_in[0];
  const float* kin = (const float*)d_in[1];
  const float* vin = (const float*)d_in[2];
  const int*   msk = (const int*)d_in[3];
  const float* Wq  = (const float*)d_in[4];
  const float* Wk  = (const float*)d_in[5];
  const float* Wv  = (const float*)d_in[6];
  const float* Wo  = (const float*)d_in[7];
  const float* bo  = (const float*)d_in[8];
  unsigned short* ws = (unsigned short*)d_ws;
  const size_t EE = (size_t)Ee * Ee;

  // 1) convert inputs + weights to bf16
  cvt_batch<<<dim3((unsigned)(SZ_X / 4 / 256), 1, 3), 256, 0, stream>>>(
      qin, kin, vin, nullptr, ws + OFF_XQ, SZ_X, (int)(SZ_X / 4));
  cvt_batch<<<dim3((unsigned)(EE / 4 / 256), 1, 4), 256, 0, stream>>>(
      Wq, Wk, Wv, Wo, ws + OFF_W, EE, (int)(EE / 4));

  // 2a) Q/K projections (z-batched):  C[m][e] = X @ W^T
  gemm_bt<false><<<dim3(8, 32, 2), 256, 0, stream>>>(
      ws + OFF_XQ, ws + OFF_W, ws + OFF_QB, nullptr, nullptr,
      SZ_X, EE, SZ_X, Ee);

  // 2b) V projection, TRANSPOSED output:  Vt[e][m] = Wv @ Xv^T
  gemm_bt<false><<<dim3(32, 8, 1), 256, 0, stream>>>(
      ws + OFF_W + 2 * EE, ws + OFF_XQ + 2 * SZ_X, ws + OFF_VB, nullptr, nullptr,
      0, 0, 0, Ms);

  // 3) masked attention (1D grid 512, XCD-swizzled, inline int32 mask)
  attn_kernel<<<dim3(512), 256, 0, stream>>>(
      ws + OFF_QB, ws + OFF_KB, ws + OFF_VB, msk, ws + OFF_ATTN);

  // 4) output projection + bias -> fp32 d_out
  gemm_bt<true><<<dim3(8, 32, 1), 256, 0, stream>>>(
      ws + OFF_ATTN, ws + OFF_W + 3 * EE, nullptr,
      (float*)d_out, bo, 0, 0, 0, Ee);
}

// Round 8
// 243.452 us; speedup vs baseline: 2.1004x; 1.0154x over previous
//
#include <hip/hip_runtime.h>
#include <hip/hip_bf16.h>

#define DEVI __device__ __forceinline__

typedef __bf16 bf16x8 __attribute__((ext_vector_type(8)));
typedef float f32x4 __attribute__((ext_vector_type(4)));
typedef unsigned short u16x4 __attribute__((ext_vector_type(4)));
typedef unsigned int u32x2 __attribute__((ext_vector_type(2)));
typedef int i32x4 __attribute__((ext_vector_type(4)));

constexpr int Nn = 2, Ss = 2048, Ee = 1024, Hh = 16;
constexpr int Ms = Nn * Ss;                       // 4096 rows
constexpr float SCALE = 0.022097086912079608f;    // 1/sqrt(2048) -- key-length scaling!

// workspace layout (bf16 elements)
constexpr size_t SZ_X   = (size_t)Ms * Ee;        // 4,194,304
constexpr size_t OFF_QB = 0;                      // Q projected [Ms][Ee]
constexpr size_t OFF_KB = SZ_X;                   // K projected [Ms][Ee]
constexpr size_t OFF_VB = 2 * SZ_X;               // V projected TRANSPOSED [Ee][Ms]
constexpr size_t OFF_XQ = 3 * SZ_X;               // bf16 inputs (3)
constexpr size_t OFF_W  = 6 * SZ_X;               // 4 weights, each Ee*Ee
constexpr size_t OFF_ATTN = OFF_XQ;               // attention out aliases XQ (dead by then)

DEVI unsigned short f2bf(float f) {               // RNE f32->bf16 (no NaN in this data)
  unsigned int u = __builtin_bit_cast(unsigned int, f);
  u += 0x7fffu + ((u >> 16) & 1u);
  return (unsigned short)(u >> 16);
}

DEVI void async16(const void* g, void* l) {
  __builtin_amdgcn_global_load_lds(
      (const __attribute__((address_space(1))) void*)g,
      (__attribute__((address_space(3))) void*)l, 16, 0, 0);
}

DEVI f32x4 mfma_bf16(bf16x8 a, bf16x8 b, f32x4 c) {
  return __builtin_amdgcn_mfma_f32_16x16x32_bf16(a, b, c, 0, 0, 0);
}

DEVI unsigned cvt_pk_bf16(float lo, float hi) {   // v_cvt_pk_bf16_f32: [hi|lo]
  unsigned r;
  asm("v_cvt_pk_bf16_f32 %0, %1, %2" : "=v"(r) : "v"(lo), "v"(hi));
  return r;
}

// ---------------- fp32 -> bf16 convert, z-batched over up to 4 sources -------------
__global__ __launch_bounds__(256) void cvt_batch(
    const float* __restrict__ s0, const float* __restrict__ s1,
    const float* __restrict__ s2, const float* __restrict__ s3,
    unsigned short* __restrict__ dbase, size_t dstride, int n4)
{
  const float* s = (blockIdx.z == 0) ? s0 : (blockIdx.z == 1) ? s1
                 : (blockIdx.z == 2) ? s2 : s3;
  unsigned short* d = dbase + (size_t)blockIdx.z * dstride;
  const int i = blockIdx.x * 256 + threadIdx.x;
  if (i >= n4) return;
  const float4 v = reinterpret_cast<const float4*>(s)[i];
  u16x4 o = { f2bf(v.x), f2bf(v.y), f2bf(v.z), f2bf(v.w) };
  reinterpret_cast<u16x4*>(d)[i] = o;
}

// ---------------- 128x128 bf16 GEMM, C = A @ B^T  (A:[M,K=1024], B:[N,K=1024]) -----
template <bool WRITE_F32>
__global__ __launch_bounds__(256) void gemm_bt(
    const unsigned short* __restrict__ Abase,
    const unsigned short* __restrict__ Bbase,
    unsigned short* __restrict__ Cbase,
    float* __restrict__ Cf,
    const float* __restrict__ bias,
    size_t strideA, size_t strideB, size_t strideC, int ldC)
{
  constexpr int K = 1024;
  __shared__ unsigned short As[128 * 32];
  __shared__ unsigned short Bs[128 * 32];

  const int z = blockIdx.z;
  const unsigned short* A = Abase + (size_t)z * strideA;
  const unsigned short* B = Bbase + (size_t)z * strideB;

  const int tid = threadIdx.x;
  const int lane = tid & 63, w = tid >> 6;
  const int lr = lane & 15, lg = lane >> 4;
  const int m0 = blockIdx.y * 128, n0 = blockIdx.x * 128;
  const int wr = (w >> 1) * 64, wc = (w & 1) * 64;

  const f32x4 zero = {0.f, 0.f, 0.f, 0.f};
  f32x4 acc[4][4];
  for (int a = 0; a < 4; ++a)
    for (int b = 0; b < 4; ++b) acc[a][b] = zero;

  for (int k0 = 0; k0 < K; k0 += 32) {
#pragma unroll
    for (int ii = 0; ii < 2; ++ii) {
      const int i = 2 * w + ii;
      const int boff = i * 1024 + lane * 16;
      const int row = boff >> 6;
      const int colb = boff & 63;
      const char* ga = (const char*)A + ((size_t)(m0 + row) * K + k0) * 2 + colb;
      const char* gb = (const char*)B + ((size_t)(n0 + row) * K + k0) * 2 + colb;
      async16(ga, (char*)As + i * 1024);
      async16(gb, (char*)Bs + i * 1024);
    }
    __syncthreads();

    bf16x8 aF[4], bF[4];
#pragma unroll
    for (int rb = 0; rb < 4; ++rb)
      aF[rb] = *(const bf16x8*)(As + (wr + rb * 16 + lr) * 32 + lg * 8);
#pragma unroll
    for (int cb = 0; cb < 4; ++cb)
      bF[cb] = *(const bf16x8*)(Bs + (wc + cb * 16 + lr) * 32 + lg * 8);
#pragma unroll
    for (int rb = 0; rb < 4; ++rb)
#pragma unroll
      for (int cb = 0; cb < 4; ++cb)
        acc[rb][cb] = mfma_bf16(aF[rb], bF[cb], acc[rb][cb]);
    __syncthreads();
  }

#pragma unroll
  for (int rb = 0; rb < 4; ++rb) {
#pragma unroll
    for (int cb = 0; cb < 4; ++cb) {
#pragma unroll
      for (int j = 0; j < 4; ++j) {
        const int row = m0 + wr + rb * 16 + lg * 4 + j;
        const int col = n0 + wc + cb * 16 + lr;
        const float v = acc[rb][cb][j];
        if constexpr (WRITE_F32) {
          Cf[(size_t)row * ldC + col] = v + bias[col];
        } else {
          unsigned short* C = Cbase + (size_t)z * strideC;
          C[(size_t)row * ldC + col] = f2bf(v);
        }
      }
    }
  }
}

// ---------------- fused masked attention, deep-pipelined ---------------------------
// S^T orientation (mfma(K,Q)). Pipeline depths: mask prefetch 2 tiles ahead
// (3 register sets, the HBM-latency item), K/V staging 1 ahead (L2-resident).
// Top-of-iteration wait is vmcnt(8): requires stage(t)+mask(t) landed, leaves the
// newest 8 mask loads in flight across the barrier (never a full drain mid-loop).
// Issue order ST-before-MASK is pinned with sched_barrier so the FIFO count holds.
__global__ __launch_bounds__(256) void attn_kernel(
    const unsigned short* __restrict__ Qb,
    const unsigned short* __restrict__ Kb,     // [Ms][Ee]
    const unsigned short* __restrict__ Vtb,    // [Ee][Ms]  (pre-transposed)
    const int* __restrict__ mask,
    unsigned short* __restrict__ Ob)
{
  __shared__ unsigned short Kl0[64 * 64], Kl1[64 * 64];
  __shared__ unsigned short Vl0[64 * 64], Vl1[64 * 64];
  __shared__ unsigned short Pw[4 * 32 * 72];   // per-wave P [32 q][144 B rows]

  const int tid = threadIdx.x;
  const int lane = tid & 63, w = tid >> 6;
  const int lr = lane & 15, lg = lane >> 4;

  // XCD-locality decode
  const int lid = blockIdx.x;
  const int xcd = lid & 7, slot = lid >> 3;
  const int g = xcd + 8 * (slot >> 4);           // nh group 0..31
  const int n = g >> 4, h = g & 15;
  const int q0 = (slot & 15) * 128;

  // Q fragments: wave w owns q rows [q0+32w, q0+32w+32)
  bf16x8 aQ[2][2];
#pragma unroll
  for (int qb = 0; qb < 2; ++qb) {
    const unsigned short* qp =
        Qb + ((size_t)(n * Ss + q0 + w * 32 + qb * 16 + lr)) * Ee + h * 64 + lg * 8;
    aQ[qb][0] = *(const bf16x8*)(qp);
    aQ[qb][1] = *(const bf16x8*)(qp + 32);
  }

  // staging geometry (16B chunk sig of the 8KB [64][64] tile, source pre-swizzled)
  const int sig0 = (w * 2) * 64 + lane;
  const int row0 = sig0 >> 3;
  const int c0 = (sig0 & 7) ^ (row0 & 7);
  const int row1 = row0 + 8;
  const int c1 = (sig0 & 7) ^ (row1 & 7);
  const int ldsb0 = (w * 2 + 0) * 1024;
  const int ldsb1 = (w * 2 + 1) * 1024;

  const unsigned short* kp0 = Kb + ((size_t)(n * Ss + row0) * Ee + h * 64 + c0 * 8);
  const unsigned short* kp1 = Kb + ((size_t)(n * Ss + row1) * Ee + h * 64 + c1 * 8);
  const unsigned short* vp0 = Vtb + ((size_t)(h * 64 + row0) * Ms + n * Ss + c0 * 8);
  const unsigned short* vp1 = Vtb + ((size_t)(h * 64 + row1) * Ms + n * Ss + c1 * 8);

  const int* m0p = mask + ((size_t)(n * Hh + h) * Ss + (q0 + w * 32 + lr)) * Ss
                        + lg * 4;
  const int* m1p = m0p + (size_t)16 * Ss;

  // precomputed swizzled DS byte offsets (per-thread constants)
  int koff[4][2];                                // K/V frag reads (same formula)
#pragma unroll
  for (int cb = 0; cb < 4; ++cb) {
    const int row = cb * 16 + lr;
    koff[cb][0] = row * 128 + ((lg ^ (row & 7)) * 16);
    koff[cb][1] = row * 128 + (((4 + lg) ^ (row & 7)) * 16);
  }
  char* const PwW = (char*)Pw + w * (32 * 144);
  int pwo[2], pro[2];                            // P write / read bases per qb
#pragma unroll
  for (int qb = 0; qb < 2; ++qb) {
    pwo[qb] = (qb * 16 + lr) * 144 + lg * 8;
    pro[qb] = (qb * 16 + lr) * 144 + lg * 16;
  }

  const f32x4 zero = {0.f, 0.f, 0.f, 0.f};
  f32x4 oacc[2][4];
#pragma unroll
  for (int qb = 0; qb < 2; ++qb)
#pragma unroll
    for (int db = 0; db < 4; ++db) oacc[qb][db] = zero;
  float rs[2] = {0.f, 0.f};

  // ---- prologue: stage t0 -> buf0 (4 VMEM), then mask t0 -> A, t1 -> B (16) ----
  async16(kp0, (char*)Kl0 + ldsb0);
  async16(kp1, (char*)Kl0 + ldsb1);
  async16(vp0, (char*)Vl0 + ldsb0);
  async16(vp1, (char*)Vl0 + ldsb1);
  kp0 += (size_t)64 * Ee; kp1 += (size_t)64 * Ee; vp0 += 64; vp1 += 64;
  __builtin_amdgcn_sched_barrier(0);

  i32x4 mqA[2][4], mqB[2][4], mqC[2][4];
#pragma unroll
  for (int cb = 0; cb < 4; ++cb) {
    mqA[0][cb] = __builtin_nontemporal_load((const i32x4*)(m0p + cb * 16));
    mqA[1][cb] = __builtin_nontemporal_load((const i32x4*)(m1p + cb * 16));
  }
#pragma unroll
  for (int cb = 0; cb < 4; ++cb) {
    mqB[0][cb] = __builtin_nontemporal_load((const i32x4*)(m0p + 64 + cb * 16));
    mqB[1][cb] = __builtin_nontemporal_load((const i32x4*)(m1p + 64 + cb * 16));
  }
  __builtin_amdgcn_sched_barrier(0);

  auto tile = [&](const unsigned short* KC, const unsigned short* VC,
                  unsigned short* KN, unsigned short* VN,
                  i32x4 (&MQC)[2][4], i32x4 (&MQN)[2][4],
                  bool do_stage, bool do_mask, bool last) {
    // stage(t) + mask(t) have landed; newest 8 (mask t+1) may stay in flight
    if (last) asm volatile("s_waitcnt vmcnt(0)" ::: "memory");
    else      asm volatile("s_waitcnt vmcnt(8)" ::: "memory");
    __builtin_amdgcn_s_barrier();

    if (do_stage) {                      // stage(t+1) -> other KV buffer (4 VMEM)
      async16(kp0, (char*)KN + ldsb0);
      async16(kp1, (char*)KN + ldsb1);
      async16(vp0, (char*)VN + ldsb0);
      async16(vp1, (char*)VN + ldsb1);
      kp0 += (size_t)64 * Ee; kp1 += (size_t)64 * Ee; vp0 += 64; vp1 += 64;
    }
    __builtin_amdgcn_sched_barrier(0);   // pin ST-before-MASK issue order
    if (do_mask) {                       // mask(t+2) -> rotating set (8 VMEM)
#pragma unroll
      for (int cb = 0; cb < 4; ++cb) {
        MQN[0][cb] = __builtin_nontemporal_load((const i32x4*)(m0p + 128 + cb * 16));
        MQN[1][cb] = __builtin_nontemporal_load((const i32x4*)(m1p + 128 + cb * 16));
      }
    }
    __builtin_amdgcn_sched_barrier(0);
    m0p += 64; m1p += 64;

    // S^T = K Q^T per 16-k block; gated exp; cvt_pk pack; ds_write_b64
#pragma unroll
    for (int cb = 0; cb < 4; ++cb) {
      const bf16x8 kF0 = *(const bf16x8*)((const char*)KC + koff[cb][0]);
      const bf16x8 kF1 = *(const bf16x8*)((const char*)KC + koff[cb][1]);
#pragma unroll
      for (int qb = 0; qb < 2; ++qb) {
        f32x4 a = mfma_bf16(kF0, aQ[qb][0], zero);
        a = mfma_bf16(kF1, aQ[qb][1], a);
        float p[4];
#pragma unroll
        for (int j = 0; j < 4; ++j)
          p[j] = MQC[qb][cb][j] ? __expf(a[j] * SCALE) : 0.f;
        rs[qb] += (p[0] + p[1]) + (p[2] + p[3]);
        u32x2 pd = { cvt_pk_bf16(p[0], p[1]), cvt_pk_bf16(p[2], p[3]) };
        *(u32x2*)(PwW + pwo[qb] + cb * 32) = pd;
      }
    }

    // O += P V  (Pw rows wave-private; compiler orders the LDS RAW via lgkmcnt)
    bf16x8 aP[2][2];
#pragma unroll
    for (int qb = 0; qb < 2; ++qb) {
      aP[qb][0] = *(const bf16x8*)(PwW + pro[qb]);
      aP[qb][1] = *(const bf16x8*)(PwW + pro[qb] + 64);
    }
#pragma unroll
    for (int db = 0; db < 4; ++db) {
#pragma unroll
      for (int kc = 0; kc < 2; ++kc) {
        const bf16x8 bV = *(const bf16x8*)((const char*)VC + koff[db][kc]);
#pragma unroll
        for (int qb = 0; qb < 2; ++qb)
          oacc[qb][db] = mfma_bf16(aP[qb][kc], bV, oacc[qb][db]);
      }
    }
  };

  // 30 steady-state tiles (period-6 unroll: KV parity 2 x mask rotation 3)
  for (int kt6 = 0; kt6 < 5; ++kt6) {
    tile(Kl0, Vl0, Kl1, Vl1, mqA, mqC, true, true, false);   // t%6==0
    tile(Kl1, Vl1, Kl0, Vl0, mqB, mqA, true, true, false);   // t%6==1
    tile(Kl0, Vl0, Kl1, Vl1, mqC, mqB, true, true, false);   // t%6==2
    tile(Kl1, Vl1, Kl0, Vl0, mqA, mqC, true, true, false);   // t%6==3
    tile(Kl0, Vl0, Kl1, Vl1, mqB, mqA, true, true, false);   // t%6==4
    tile(Kl1, Vl1, Kl0, Vl0, mqC, mqB, true, true, false);   // t%6==5
  }
  // t=30: stage t31, no mask prefetch;  t=31: drain
  tile(Kl0, Vl0, Kl1, Vl1, mqA, mqC, true, false, false);
  tile(Kl1, Vl1, Kl0, Vl0, mqB, mqA, false, false, true);

  // rowsum: reduce across the 4 lg groups (q = qb*16+lr), then fetch per-output-q
  float inv[2][4];
#pragma unroll
  for (int qb = 0; qb < 2; ++qb) {
    float r = rs[qb];
    r += __shfl_xor(r, 16, 64);
    r += __shfl_xor(r, 32, 64);
#pragma unroll
    for (int j = 0; j < 4; ++j)
      inv[qb][j] = 1.0f / __shfl(r, lg * 4 + j, 64);
  }
#pragma unroll
  for (int qb = 0; qb < 2; ++qb)
#pragma unroll
    for (int db = 0; db < 4; ++db)
#pragma unroll
      for (int j = 0; j < 4; ++j) {
        const int qr = q0 + w * 32 + qb * 16 + lg * 4 + j;
        Ob[((size_t)(n * Ss + qr)) * Ee + h * 64 + db * 16 + lr] =
            f2bf(oacc[qb][db][j] * inv[qb][j]);
      }
}

// -----------------------------------------------------------------------------------
extern "C" void kernel_launch(void* const* d_in, const int* in_sizes, int n_in,
                              void* d_out, int out_size, void* d_ws, size_t ws_size,
                              hipStream_t stream) {
  const float* qin = (const float*)d_in[0];
  const float* kin = (const float*)d_in[1];
  const float* vin = (const float*)d_in[2];
  const int*   msk = (const int*)d_in[3];
  const float* Wq  = (const float*)d_in[4];
  const float* Wk  = (const float*)d_in[5];
  const float* Wv  = (const float*)d_in[6];
  const float* Wo  = (const float*)d_in[7];
  const float* bo  = (const float*)d_in[8];
  unsigned short* ws = (unsigned short*)d_ws;
  const size_t EE = (size_t)Ee * Ee;

  // 1) convert inputs + weights to bf16
  cvt_batch<<<dim3((unsigned)(SZ_X / 4 / 256), 1, 3), 256, 0, stream>>>(
      qin, kin, vin, nullptr, ws + OFF_XQ, SZ_X, (int)(SZ_X / 4));
  cvt_batch<<<dim3((unsigned)(EE / 4 / 256), 1, 4), 256, 0, stream>>>(
      Wq, Wk, Wv, Wo, ws + OFF_W, EE, (int)(EE / 4));

  // 2a) Q/K projections (z-batched):  C[m][e] = X @ W^T
  gemm_bt<false><<<dim3(8, 32, 2), 256, 0, stream>>>(
      ws + OFF_XQ, ws + OFF_W, ws + OFF_QB, nullptr, nullptr,
      SZ_X, EE, SZ_X, Ee);

  // 2b) V projection, TRANSPOSED output:  Vt[e][m] = Wv @ Xv^T
  gemm_bt<false><<<dim3(32, 8, 1), 256, 0, stream>>>(
      ws + OFF_W + 2 * EE, ws + OFF_XQ + 2 * SZ_X, ws + OFF_VB, nullptr, nullptr,
      0, 0, 0, Ms);

  // 3) masked attention (1D grid 512, XCD-swizzled, deep-pipelined mask stream)
  attn_kernel<<<dim3(512), 256, 0, stream>>>(
      ws + OFF_QB, ws + OFF_KB, ws + OFF_VB, msk, ws + OFF_ATTN);

  // 4) output projection + bias -> fp32 d_out
  gemm_bt<true><<<dim3(8, 32, 1), 256, 0, stream>>>(
      ws + OFF_ATTN, ws + OFF_W + 3 * EE, nullptr,
      (float*)d_out, bo, 0, 0, 0, Ee);
}